// Round 11
// baseline (4157.008 us; speedup 1.0000x reference)
//
#include <hip/hip_runtime.h>
#include <math.h>

// Problem dims
#define TT 128
#define BB 512
#define EE 100
#define HH 256
#define G4 1024        // 4*H
#define NTAG 20
#define NCH 92         // K-chunks of 4: 368/4
#define PW3SZ (NCH * 4096)   // 376832  [chunk][n][kk]
#define QP2SZ (16 * 1600)    // 25600   [kqb][e][q][kk]
#define RP3SZ (7 * 4096)     // 28672   [kqb][j][q][kk] (k>=100 zero)

__device__ __forceinline__ float sigm(float x) { return 1.0f / (1.0f + expf(-x)); }

// ---------------------------------------------------------------------------
// prep7 (one direction): chunk-contiguous packed layouts.
// PW3[chunk*4096 + n*4 + kk] = W[k=chunk*4+kk][n]  (k<100: Wih^T, <356: Whh^T, else 0)
// QP2[kqb*1600 + e*16 + q*4 + kk] = Q[k=(kqb*4+q)*4+kk][e]          (k<256)
// RP3[kqb*4096 + j*16 + q*4 + kk] = R[k][j] for k<100 else 0        (k<112)
// bP[n] = bih[n] + bhh[n]
// ---------------------------------------------------------------------------
__global__ void prep7(const float* __restrict__ Wih, const float* __restrict__ Whh,
                      const float* __restrict__ bih, const float* __restrict__ bhh,
                      const float* __restrict__ Q, const float* __restrict__ R,
                      float* __restrict__ PW3, float* __restrict__ QP2,
                      float* __restrict__ RP3, float* __restrict__ bP)
{
    int idx = blockIdx.x * blockDim.x + threadIdx.x;
    if (idx < PW3SZ) {
        int chunk = idx >> 12, rem = idx & 4095;
        int n = rem >> 2, kk = rem & 3;
        int k = chunk * 4 + kk;
        PW3[idx] = (k < EE) ? Wih[n * EE + k]
                 : (k < EE + HH) ? Whh[n * HH + (k - EE)] : 0.f;
    } else if (idx < PW3SZ + QP2SZ) {
        int i = idx - PW3SZ;
        int kqb = i / 1600, rem = i - kqb * 1600;
        int e = rem >> 4, q = (rem >> 2) & 3, kk = rem & 3;
        int k = (kqb * 4 + q) * 4 + kk;
        QP2[i] = Q[k * EE + e];
    } else if (idx < PW3SZ + QP2SZ + RP3SZ) {
        int i = idx - (PW3SZ + QP2SZ);
        int kqb = i >> 12, rem = i & 4095;
        int j = rem >> 4, q = (rem >> 2) & 3, kk = rem & 3;
        int k = (kqb * 4 + q) * 4 + kk;
        RP3[i] = (k < EE) ? R[k * HH + j] : 0.f;
    } else if (idx < PW3SZ + QP2SZ + RP3SZ + G4) {
        int n = idx - (PW3SZ + QP2SZ + RP3SZ);
        bP[n] = bih[n] + bhh[n];
    }
}

// ---- p3 slot macros --------------------------------------------------------
// W##S##i = col n0+i, components kk0..3 ; X##S##kk = k-elem kk, components rows 0..3
#define P3L(S, c) { const int cc_ = ((c) <= 45) ? (c) : 45; \
    const float* wp_ = PWd + (size_t)(cbase + cc_) * 4096 + n0 * 4; \
    W##S##0 = *(const float4*)(wp_);      W##S##1 = *(const float4*)(wp_ + 4); \
    W##S##2 = *(const float4*)(wp_ + 8);  W##S##3 = *(const float4*)(wp_ + 12); \
    const float* xp_ = sAT + (cbase + cc_) * 16; \
    X##S##0 = *(const float4*)(xp_);      X##S##1 = *(const float4*)(xp_ + 4); \
    X##S##2 = *(const float4*)(xp_ + 8);  X##S##3 = *(const float4*)(xp_ + 12); }

#define P3F(S) { \
    a00 += (X##S##0).x*(W##S##0).x + (X##S##1).x*(W##S##0).y + (X##S##2).x*(W##S##0).z + (X##S##3).x*(W##S##0).w; \
    a01 += (X##S##0).x*(W##S##1).x + (X##S##1).x*(W##S##1).y + (X##S##2).x*(W##S##1).z + (X##S##3).x*(W##S##1).w; \
    a02 += (X##S##0).x*(W##S##2).x + (X##S##1).x*(W##S##2).y + (X##S##2).x*(W##S##2).z + (X##S##3).x*(W##S##2).w; \
    a03 += (X##S##0).x*(W##S##3).x + (X##S##1).x*(W##S##3).y + (X##S##2).x*(W##S##3).z + (X##S##3).x*(W##S##3).w; \
    a10 += (X##S##0).y*(W##S##0).x + (X##S##1).y*(W##S##0).y + (X##S##2).y*(W##S##0).z + (X##S##3).y*(W##S##0).w; \
    a11 += (X##S##0).y*(W##S##1).x + (X##S##1).y*(W##S##1).y + (X##S##2).y*(W##S##1).z + (X##S##3).y*(W##S##1).w; \
    a12 += (X##S##0).y*(W##S##2).x + (X##S##1).y*(W##S##2).y + (X##S##2).y*(W##S##2).z + (X##S##3).y*(W##S##2).w; \
    a13 += (X##S##0).y*(W##S##3).x + (X##S##1).y*(W##S##3).y + (X##S##2).y*(W##S##3).z + (X##S##3).y*(W##S##3).w; \
    a20 += (X##S##0).z*(W##S##0).x + (X##S##1).z*(W##S##0).y + (X##S##2).z*(W##S##0).z + (X##S##3).z*(W##S##0).w; \
    a21 += (X##S##0).z*(W##S##1).x + (X##S##1).z*(W##S##1).y + (X##S##2).z*(W##S##1).z + (X##S##3).z*(W##S##1).w; \
    a22 += (X##S##0).z*(W##S##2).x + (X##S##1).z*(W##S##2).y + (X##S##2).z*(W##S##2).z + (X##S##3).z*(W##S##2).w; \
    a23 += (X##S##0).z*(W##S##3).x + (X##S##1).z*(W##S##3).y + (X##S##2).z*(W##S##3).z + (X##S##3).z*(W##S##3).w; \
    a30 += (X##S##0).w*(W##S##0).x + (X##S##1).w*(W##S##0).y + (X##S##2).w*(W##S##0).z + (X##S##3).w*(W##S##0).w; \
    a31 += (X##S##0).w*(W##S##1).x + (X##S##1).w*(W##S##1).y + (X##S##2).w*(W##S##1).z + (X##S##3).w*(W##S##1).w; \
    a32 += (X##S##0).w*(W##S##2).x + (X##S##1).w*(W##S##2).y + (X##S##2).w*(W##S##2).z + (X##S##3).w*(W##S##2).w; \
    a33 += (X##S##0).w*(W##S##3).x + (X##S##1).w*(W##S##3).y + (X##S##2).w*(W##S##3).z + (X##S##3).w*(W##S##3).w; }

// ---------------------------------------------------------------------------
// Main recurrence. 256 independent blocks (128 chunks x 2 dirs), 512 thr,
// 4 batch rows, 1024 gate cols. Phase 3 K-SPLIT: threads 0-255 do k-chunks
// 0..45, threads 256-511 do 46..91, BOTH for all 4 rows x their 4 cols ->
// W is read exactly once per block-step (halves L2 weight traffic); partial
// sums reduced through 2-bank sG. Transposed sAT[k][4r] makes each X b128
// deliver all 4 rows; chunk-contiguous layouts fold all offsets to imms.
// ---------------------------------------------------------------------------
__global__ __launch_bounds__(512, 1) void lstm7(
    const int* __restrict__ words, const float* __restrict__ embed,
    const float* __restrict__ QPf, const float* __restrict__ RPf,
    const float* __restrict__ PWf, const float* __restrict__ bPf,
    const float* __restrict__ QPb, const float* __restrict__ RPb,
    const float* __restrict__ PWb, const float* __restrict__ bPb,
    float* hfbuf, float* hbbuf)
{
    const int bid = blockIdx.x;
    const int dir = bid & 1;
    const int cb  = bid >> 1;         // 0..127
    const int b0  = cb * 4;
    const int tid = threadIdx.x;

    const float* QPd = dir ? QPb : QPf;
    const float* RPd = dir ? RPb : RPf;
    const float* PWd = dir ? PWb : PWf;
    const float* bP  = dir ? bPb : bPf;
    float* hout = dir ? hbbuf : hfbuf;

    __shared__ alignas(16) float sAT[368 * 4];    // [k][4 rows], 5.75 KB
    __shared__ alignas(16) float sAlin[4 * 112];  // xm row-major (p2), 1.75 KB
    __shared__ alignas(16) float sH[4 * HH];      // h_prev row-major, 4 KB
    __shared__ alignas(16) float sG[2 * 4 * G4];  // partial gates [g][r][n], 32 KB
    __shared__ int sWords[4 * TT];

    // phase-1: 1 row x 1 e-col
    const int e  = tid & 127;
    const int r1 = tid >> 7;
    // phase-2: 2 rows x 1 j-col
    const int j2  = tid & 255;
    const int r20 = (tid >> 8) * 2, r21 = r20 + 1;
    // phase-3: 4 rows x 4 cols, K-split by thread half
    const int n0    = (tid & 255) * 4;
    const int g3    = tid >> 8;              // 0 or 1
    const int cbase = g3 * 46;
    // phase-4: 2 rows x 1 col
    const int j4  = tid & 255;
    const int r4a = (tid >> 8) * 2, r4b = r4a + 1;
    float c0 = 0.f, c1 = 0.f;

    const float4 bvr = *(const float4*)(bP + n0);
    const float4 bv  = (g3 == 0) ? bvr : make_float4(0.f, 0.f, 0.f, 0.f);

    // preload word ids; zero sAT k-pad (356..367) and sAlin col-pad (100..111)
    sWords[tid & 511] = words[(b0 + (tid >> 7)) * TT + (tid & 127)];
    if (tid < 48)  sAT[(356 + (tid >> 2)) * 4 + (tid & 3)] = 0.f;
    if (tid >= 64 && tid < 112) {
        const int i = tid - 64, r = i / 12, p = i - r * 12;
        sAlin[r * 112 + 100 + p] = 0.f;
    }
    __syncthreads();

    for (int s = 0; s < TT; ++s) {
        const int t = dir ? (TT - 1 - s) : s;

        // ---- phase 1: xm[r][e] = 2*sig(h_prev[r] . Q[:,e]) * x_t[r][e] ----
        if (e < EE) {
            const int w = sWords[r1 * TT + t];
            const float x = __builtin_nontemporal_load(&embed[(size_t)w * EE + e]);
            if (s == 0) {
                sAT[e * 4 + r1] = x;
                sAlin[r1 * 112 + e] = x;
            } else {
                float ac0 = 0.f, ac1 = 0.f, ac2 = 0.f, ac3 = 0.f;
                const float* hp0 = sH + r1 * HH;
                #pragma unroll
                for (int kqb = 0; kqb < 16; ++kqb) {
                    const float* qp = QPd + kqb * 1600 + e * 16;
                    const float4 q0 = *(const float4*)(qp);
                    const float4 q1 = *(const float4*)(qp + 4);
                    const float4 q2 = *(const float4*)(qp + 8);
                    const float4 q3 = *(const float4*)(qp + 12);
                    const float4 h0 = *(const float4*)(hp0 + kqb * 16);
                    const float4 h1 = *(const float4*)(hp0 + kqb * 16 + 4);
                    const float4 h2 = *(const float4*)(hp0 + kqb * 16 + 8);
                    const float4 h3 = *(const float4*)(hp0 + kqb * 16 + 12);
                    ac0 += h0.x*q0.x + h0.y*q0.y + h0.z*q0.z + h0.w*q0.w;
                    ac1 += h1.x*q1.x + h1.y*q1.y + h1.z*q1.z + h1.w*q1.w;
                    ac2 += h2.x*q2.x + h2.y*q2.y + h2.z*q2.z + h2.w*q2.w;
                    ac3 += h3.x*q3.x + h3.y*q3.y + h3.z*q3.z + h3.w*q3.w;
                }
                const float xm = 2.f * sigm((ac0 + ac1) + (ac2 + ac3)) * x;
                sAT[e * 4 + r1] = xm;
                sAlin[r1 * 112 + e] = xm;
            }
        }
        __syncthreads();

        // ---- phase 2: hm[r][j] = 2*sig(xm[r] . R[:,j]) * h_prev[r][j] ----
        if (s == 0) {
            sAT[(100 + j2) * 4 + r20] = 0.f;
            sAT[(100 + j2) * 4 + r21] = 0.f;
        } else {
            float s0a = 0.f, s0b = 0.f, s1a = 0.f, s1b = 0.f;
            const float* x0p = sAlin + r20 * 112;
            const float* x1p = sAlin + r21 * 112;
            #pragma unroll
            for (int kqb = 0; kqb < 7; ++kqb) {
                const float* rp = RPd + kqb * 4096 + j2 * 16;
                const float4 w0 = *(const float4*)(rp);
                const float4 w1 = *(const float4*)(rp + 4);
                const float4 w2 = *(const float4*)(rp + 8);
                const float4 w3 = *(const float4*)(rp + 12);
                const float4 xa0 = *(const float4*)(x0p + kqb * 16);
                const float4 xa1 = *(const float4*)(x0p + kqb * 16 + 4);
                const float4 xa2 = *(const float4*)(x0p + kqb * 16 + 8);
                const float4 xa3 = *(const float4*)(x0p + kqb * 16 + 12);
                const float4 xb0 = *(const float4*)(x1p + kqb * 16);
                const float4 xb1 = *(const float4*)(x1p + kqb * 16 + 4);
                const float4 xb2 = *(const float4*)(x1p + kqb * 16 + 8);
                const float4 xb3 = *(const float4*)(x1p + kqb * 16 + 12);
                s0a += xa0.x*w0.x + xa0.y*w0.y + xa0.z*w0.z + xa0.w*w0.w;
                s0b += xa1.x*w1.x + xa1.y*w1.y + xa1.z*w1.z + xa1.w*w1.w;
                s0a += xa2.x*w2.x + xa2.y*w2.y + xa2.z*w2.z + xa2.w*w2.w;
                s0b += xa3.x*w3.x + xa3.y*w3.y + xa3.z*w3.z + xa3.w*w3.w;
                s1a += xb0.x*w0.x + xb0.y*w0.y + xb0.z*w0.z + xb0.w*w0.w;
                s1b += xb1.x*w1.x + xb1.y*w1.y + xb1.z*w1.z + xb1.w*w1.w;
                s1a += xb2.x*w2.x + xb2.y*w2.y + xb2.z*w2.z + xb2.w*w2.w;
                s1b += xb3.x*w3.x + xb3.y*w3.y + xb3.z*w3.z + xb3.w*w3.w;
            }
            sAT[(100 + j2) * 4 + r20] = 2.f * sigm(s0a + s0b) * sH[r20 * HH + j2];
            sAT[(100 + j2) * 4 + r21] = 2.f * sigm(s1a + s1b) * sH[r21 * HH + j2];
        }
        __syncthreads();

        // ---- phase 3: G-partial = [xm|hm](khalf) @ PW3 + bias(g=0 only) ---
        {
            float a00=bv.x,a01=bv.y,a02=bv.z,a03=bv.w;
            float a10=bv.x,a11=bv.y,a12=bv.z,a13=bv.w;
            float a20=bv.x,a21=bv.y,a22=bv.z,a23=bv.w;
            float a30=bv.x,a31=bv.y,a32=bv.z,a33=bv.w;
            float4 WA0,WA1,WA2,WA3,XA0,XA1,XA2,XA3;
            float4 WB0,WB1,WB2,WB3,XB0,XB1,XB2,XB3;
            float4 WC0,WC1,WC2,WC3,XC0,XC1,XC2,XC3;
            P3L(A,0); P3L(B,1); P3L(C,2);
            for (int cc = 0; cc <= 42; cc += 3) {   // 15 iterations
                P3F(A); P3L(A, cc+3);
                P3F(B); P3L(B, cc+4);
                P3F(C); P3L(C, cc+5);
            }
            P3F(A);                                  // local chunk 45
            float* sg = sG + g3 * 4096 + n0;
            *(float4*)(sg)          = make_float4(a00,a01,a02,a03);
            *(float4*)(sg + G4)     = make_float4(a10,a11,a12,a13);
            *(float4*)(sg + 2 * G4) = make_float4(a20,a21,a22,a23);
            *(float4*)(sg + 3 * G4) = make_float4(a30,a31,a32,a33);
        }
        __syncthreads();

        // ---- phase 4: reduce partials; cell update; h -> sH + hout[t] -----
        {
            const float* g0 = sG + r4a * G4;
            const float* g1 = sG + r4b * G4;
            const float gi0 = g0[j4]       + g0[4096 + j4];
            const float gf0 = g0[256 + j4] + g0[4096 + 256 + j4];
            const float gg0 = g0[512 + j4] + g0[4096 + 512 + j4];
            const float go0 = g0[768 + j4] + g0[4096 + 768 + j4];
            const float gi1 = g1[j4]       + g1[4096 + j4];
            const float gf1 = g1[256 + j4] + g1[4096 + 256 + j4];
            const float gg1 = g1[512 + j4] + g1[4096 + 512 + j4];
            const float go1 = g1[768 + j4] + g1[4096 + 768 + j4];
            c0 = sigm(gf0) * c0 + sigm(gi0) * tanhf(gg0);
            c1 = sigm(gf1) * c1 + sigm(gi1) * tanhf(gg1);
            const float h0 = sigm(go0) * tanhf(c0);
            const float h1 = sigm(go1) * tanhf(c1);
            sH[r4a * HH + j4] = h0;
            sH[r4b * HH + j4] = h1;
            __builtin_nontemporal_store(h0, &hout[((size_t)t * BB + b0 + r4a) * HH + j4]);
            __builtin_nontemporal_store(h1, &hout[((size_t)t * BB + b0 + r4b) * HH + j4]);
        }
        __syncthreads();
    }
}

// ---------------------------------------------------------------------------
// logits = [hf|hb] @ Wt^T + bt ; argmax (first index on ties) -> out[b][t]
// ---------------------------------------------------------------------------
__global__ __launch_bounds__(256) void logits_kernel(
    const float* __restrict__ hf, const float* __restrict__ hb,
    const float* __restrict__ Wt, const float* __restrict__ bt,
    int* __restrict__ out)
{
    __shared__ float sW[NTAG][2 * HH];
    __shared__ float sb[NTAG];
    const int tid = threadIdx.x;
    for (int i = tid; i < NTAG * 2 * HH; i += 256) (&sW[0][0])[i] = Wt[i];
    if (tid < NTAG) sb[tid] = bt[tid];
    __syncthreads();

    const int pos = blockIdx.x * 256 + tid;
    const int b  = pos & 511;
    const int t0 = pos >> 9;
    const int t1 = t0 + 64;

    float acc0[NTAG], acc1[NTAG];
    #pragma unroll
    for (int n = 0; n < NTAG; ++n) { acc0[n] = sb[n]; acc1[n] = sb[n]; }

    const float* f0 = hf + ((size_t)t0 * BB + b) * HH;
    const float* f1 = hf + ((size_t)t1 * BB + b) * HH;
    for (int k = 0; k < HH; k += 4) {
        const float4 a0 = *(const float4*)(f0 + k);
        const float4 a1 = *(const float4*)(f1 + k);
        #pragma unroll
        for (int n = 0; n < NTAG; ++n) {
            const float4 w = *(const float4*)&sW[n][k];
            acc0[n] += a0.x * w.x + a0.y * w.y + a0.z * w.z + a0.w * w.w;
            acc1[n] += a1.x * w.x + a1.y * w.y + a1.z * w.z + a1.w * w.w;
        }
    }
    const float* g0 = hb + ((size_t)t0 * BB + b) * HH;
    const float* g1 = hb + ((size_t)t1 * BB + b) * HH;
    for (int k = 0; k < HH; k += 4) {
        const float4 a0 = *(const float4*)(g0 + k);
        const float4 a1 = *(const float4*)(g1 + k);
        #pragma unroll
        for (int n = 0; n < NTAG; ++n) {
            const float4 w = *(const float4*)&sW[n][HH + k];
            acc0[n] += a0.x * w.x + a0.y * w.y + a0.z * w.z + a0.w * w.w;
            acc1[n] += a1.x * w.x + a1.y * w.y + a1.z * w.z + a1.w * w.w;
        }
    }

    float b0v = acc0[0]; int i0 = 0;
    float b1v = acc1[0]; int i1 = 0;
    #pragma unroll
    for (int n = 1; n < NTAG; ++n) {
        if (acc0[n] > b0v) { b0v = acc0[n]; i0 = n; }
        if (acc1[n] > b1v) { b1v = acc1[n]; i1 = n; }
    }
    out[b * TT + t0] = i0;
    out[b * TT + t1] = i1;
}

// ---------------------------------------------------------------------------
extern "C" void kernel_launch(void* const* d_in, const int* in_sizes, int n_in,
                              void* d_out, int out_size, void* d_ws, size_t ws_size,
                              hipStream_t stream)
{
    (void)in_sizes; (void)n_in; (void)out_size; (void)ws_size;

    const int*   words = (const int*)  d_in[0];
    const float* embd  = (const float*)d_in[5];
    const float* Wih_f = (const float*)d_in[6];
    const float* Whh_f = (const float*)d_in[7];
    const float* bih_f = (const float*)d_in[8];
    const float* bhh_f = (const float*)d_in[9];
    const float* Q_f   = (const float*)d_in[10];
    const float* R_f   = (const float*)d_in[11];
    const float* Wih_b = (const float*)d_in[12];
    const float* Whh_b = (const float*)d_in[13];
    const float* bih_b = (const float*)d_in[14];
    const float* bhh_b = (const float*)d_in[15];
    const float* Q_b   = (const float*)d_in[16];
    const float* R_b   = (const float*)d_in[17];
    const float* Wt    = (const float*)d_in[18];
    const float* bt    = (const float*)d_in[19];
    int* out = (int*)d_out;

    // workspace layout (floats), total ~138 MB
    float* ws   = (float*)d_ws;
    float* PW_f = ws;                         // 376832
    float* QP_f = PW_f + PW3SZ;               // 25600
    float* RP_f = QP_f + QP2SZ;               // 28672
    float* bP_f = RP_f + RP3SZ;               // 1024
    float* PW_b = bP_f + G4;
    float* QP_b = PW_b + PW3SZ;
    float* RP_b = QP_b + QP2SZ;
    float* bP_b = RP_b + RP3SZ;
    float* hf   = bP_b + G4;                  // 16777216
    float* hb   = hf + (size_t)TT * BB * HH;  // 16777216

    const int prep_grid = (PW3SZ + QP2SZ + RP3SZ + G4 + 255) / 256;
    prep7<<<prep_grid, 256, 0, stream>>>(Wih_f, Whh_f, bih_f, bhh_f, Q_f, R_f,
                                         PW_f, QP_f, RP_f, bP_f);
    prep7<<<prep_grid, 256, 0, stream>>>(Wih_b, Whh_b, bih_b, bhh_b, Q_b, R_b,
                                         PW_b, QP_b, RP_b, bP_b);
    lstm7<<<256, 512, 0, stream>>>(words, embd, QP_f, RP_f, PW_f, bP_f,
                                   QP_b, RP_b, PW_b, bP_b, hf, hb);
    logits_kernel<<<128, 256, 0, stream>>>(hf, hb, Wt, bt, out);
}